// Round 9
// baseline (597.541 us; speedup 1.0000x reference)
//
#include <hip/hip_runtime.h>
#include <math.h>

#define NBUCKET 65536

__device__ __forceinline__ float leakyrelu02(float v) { return v > 0.f ? v : 0.2f * v; }

// ============ GEMM: C[M,256] = A[M,256] @ B[256,256], fp32 ============
// 128x128 tile, 8x8 acc/thread, split-4+4 M and N mapping (conflict-free LDS reads)
__global__ __launch_bounds__(256) void k_gemm1(const float* __restrict__ A,
                                               const float* __restrict__ B,
                                               float* __restrict__ C, int M) {
  __shared__ float As[16][132];  // [k][m]
  __shared__ float Bs[16][132];  // [k][n]
  const int m0 = blockIdx.x * 128;
  const int n0 = blockIdx.y * 128;
  const int tid = threadIdx.x;
  const int tm = tid & 15;   // M: rows tm*4..+3 and 64+tm*4..+3
  const int tn = tid >> 4;   // N: cols tn*4..+3 and 64+tn*4..+3
  float acc[8][8];
#pragma unroll
  for (int i = 0; i < 8; ++i)
#pragma unroll
    for (int j = 0; j < 8; ++j) acc[i][j] = 0.f;

  const int ar = tid & 127, aseg = (tid >> 7) * 8;  // A stage: row ar, k-seg aseg
  const int br = tid >> 4, bc = (tid & 15) * 8;     // B stage: row br, cols bc..bc+7

  for (int k0 = 0; k0 < 256; k0 += 16) {
    float4 a0 = make_float4(0.f, 0.f, 0.f, 0.f);
    float4 a1 = make_float4(0.f, 0.f, 0.f, 0.f);
    if (m0 + ar < M) {
      const float* ap = A + (size_t)(m0 + ar) * 256 + k0 + aseg;
      a0 = *(const float4*)(ap);
      a1 = *(const float4*)(ap + 4);
    }
    As[aseg + 0][ar] = a0.x;
    As[aseg + 1][ar] = a0.y;
    As[aseg + 2][ar] = a0.z;
    As[aseg + 3][ar] = a0.w;
    As[aseg + 4][ar] = a1.x;
    As[aseg + 5][ar] = a1.y;
    As[aseg + 6][ar] = a1.z;
    As[aseg + 7][ar] = a1.w;
    const float* bp = B + (size_t)(k0 + br) * 256 + n0 + bc;
    *(float4*)&Bs[br][bc] = *(const float4*)(bp);
    *(float4*)&Bs[br][bc + 4] = *(const float4*)(bp + 4);
    __syncthreads();
#pragma unroll
    for (int kk = 0; kk < 16; ++kk) {
      float a[8], b[8];
      *(float4*)&a[0] = *(const float4*)&As[kk][tm * 4];
      *(float4*)&a[4] = *(const float4*)&As[kk][64 + tm * 4];
      *(float4*)&b[0] = *(const float4*)&Bs[kk][tn * 4];
      *(float4*)&b[4] = *(const float4*)&Bs[kk][64 + tn * 4];
#pragma unroll
      for (int i = 0; i < 8; ++i)
#pragma unroll
        for (int j = 0; j < 8; ++j) acc[i][j] += a[i] * b[j];
    }
    __syncthreads();
  }
#pragma unroll
  for (int i = 0; i < 8; ++i) {
    int m = m0 + ((i < 4) ? (tm * 4 + i) : (64 + tm * 4 + i - 4));
    if (m < M) {
      float4 o0 = make_float4(acc[i][0], acc[i][1], acc[i][2], acc[i][3]);
      float4 o1 = make_float4(acc[i][4], acc[i][5], acc[i][6], acc[i][7]);
      *(float4*)(C + (size_t)m * 256 + n0 + tn * 4) = o0;
      *(float4*)(C + (size_t)m * 256 + n0 + 64 + tn * 4) = o1;
    }
  }
}

// ============ attention logits for layer 1: wave per node ============
__global__ __launch_bounds__(256) void k_al1(const float* __restrict__ h_lin,
                                             const float* __restrict__ a_src,
                                             const float* __restrict__ a_dst,
                                             float* __restrict__ als,
                                             float* __restrict__ ald, int N) {
  int gid = blockIdx.x * 256 + threadIdx.x;
  int n = gid >> 6;
  int l = threadIdx.x & 63;
  if (n >= N) return;
  float4 h4 = *(const float4*)(h_lin + (size_t)n * 256 + l * 4);
  float4 vs = *(const float4*)(a_src + l * 4);
  float4 vd = *(const float4*)(a_dst + l * 4);
  float ps = h4.x * vs.x + h4.y * vs.y + h4.z * vs.z + h4.w * vs.w;
  float pd = h4.x * vd.x + h4.y * vd.y + h4.z * vd.z + h4.w * vd.w;
  ps += __shfl_xor(ps, 1); pd += __shfl_xor(pd, 1);
  ps += __shfl_xor(ps, 2); pd += __shfl_xor(pd, 2);
  ps += __shfl_xor(ps, 4); pd += __shfl_xor(pd, 4);
  if ((l & 7) == 0) {
    als[(size_t)n * 8 + (l >> 3)] = ps;
    ald[(size_t)n * 8 + (l >> 3)] = pd;
  }
}

// ============ CSR build: per-dst histogram ============
__global__ __launch_bounds__(256) void k_hist(const int* __restrict__ ei,
                                              int* __restrict__ counts, int E, int N) {
  int e = blockIdx.x * 256 + threadIdx.x;
  if (e >= E + N) return;
  int d = (e < E) ? ei[E + e] : (e - E);
  atomicAdd(&counts[d], 1);
}

// scan over Npad = 1024*chunk entries (chunk multiple of 4, counts padded+zeroed)
__global__ __launch_bounds__(1024) void k_scan(const int* __restrict__ counts,
                                               int* __restrict__ offsets,
                                               int* __restrict__ cursor, int chunk) {
  __shared__ int part[1024];
  const int t = threadIdx.x;
  const int base = t * chunk;
  int ssum = 0;
  for (int i = 0; i < chunk; i += 4) {
    int4 v = *(const int4*)(counts + base + i);
    ssum += v.x + v.y + v.z + v.w;
  }
  part[t] = ssum;
  __syncthreads();
  for (int d = 1; d < 1024; d <<= 1) {
    int v = (t >= d) ? part[t - d] : 0;
    __syncthreads();
    part[t] += v;
    __syncthreads();
  }
  int run = (t == 0) ? 0 : part[t - 1];
  for (int i = 0; i < chunk; i += 4) {
    int4 v = *(const int4*)(counts + base + i);
    int4 o;
    o.x = run; run += v.x;
    o.y = run; run += v.y;
    o.z = run; run += v.z;
    o.w = run; run += v.w;
    *(int4*)(offsets + base + i) = o;
    if (cursor) *(int4*)(cursor + base + i) = o;
  }
  if (t == 1023) offsets[1024 * chunk] = run;
}

// ============ scatter edges + precompute layer-1 edge weights ============
__global__ __launch_bounds__(256) void k_scatter_ew(
    const int* __restrict__ ei, const float* __restrict__ als1,
    const float* __restrict__ ald1, int* __restrict__ cursor,
    int* __restrict__ csr_src, int* __restrict__ csr_dst,
    float* __restrict__ ew, int E, int N) {
  int e = blockIdx.x * 256 + threadIdx.x;
  if (e >= E + N) return;
  int d, s;
  if (e < E) { d = ei[E + e]; s = ei[e]; }
  else { d = e - E; s = d; }
  int pos = atomicAdd(&cursor[d], 1);
  csr_src[pos] = s;
  csr_dst[pos] = d;
  float4 as0 = *(const float4*)(als1 + (size_t)s * 8);
  float4 as1 = *(const float4*)(als1 + (size_t)s * 8 + 4);
  float4 ad0 = *(const float4*)(ald1 + (size_t)d * 8);
  float4 ad1 = *(const float4*)(ald1 + (size_t)d * 8 + 4);
  float4 w0, w1;
  w0.x = expf(leakyrelu02(as0.x + ad0.x));
  w0.y = expf(leakyrelu02(as0.y + ad0.y));
  w0.z = expf(leakyrelu02(as0.z + ad0.z));
  w0.w = expf(leakyrelu02(as0.w + ad0.w));
  w1.x = expf(leakyrelu02(as1.x + ad1.x));
  w1.y = expf(leakyrelu02(as1.y + ad1.y));
  w1.z = expf(leakyrelu02(as1.z + ad1.z));
  w1.w = expf(leakyrelu02(as1.w + ad1.w));
  *(float4*)(ew + (size_t)pos * 8) = w0;
  *(float4*)(ew + (size_t)pos * 8 + 4) = w1;
}

// ============ layer-2 edge weights, edge-parallel ============
__global__ __launch_bounds__(256) void k_ew2(const int* __restrict__ csr_src,
                                             const int* __restrict__ csr_dst,
                                             const float* __restrict__ als2,
                                             const float* __restrict__ ald2,
                                             float* __restrict__ ew2, int Etot) {
  int t = blockIdx.x * 256 + threadIdx.x;
  if (t >= Etot) return;
  ew2[t] = expf(leakyrelu02(als2[csr_src[t]] + ald2[csr_dst[t]]));
}

// rowbuf skew: channel i stored at i + (i>>3)  (kills 8-way write conflicts)
#define RB(i) ((i) + ((i) >> 3))

// ============ GAT layer 1: 2-edge x 32-lane split, 8 rows in flight +
// fused (relu row) @ W2 (W2 direct from global/L1) -> h2, al2 ============
__global__ __launch_bounds__(256) void k_gat1(
    const float* __restrict__ h_lin, const float* __restrict__ ew,
    const float* __restrict__ b1, const int* __restrict__ offsets,
    const int* __restrict__ csr_src, const float* __restrict__ W2,
    const float* __restrict__ a_src2, const float* __restrict__ a_dst2,
    float* __restrict__ h2, float* __restrict__ als2, float* __restrict__ ald2, int N) {
  __shared__ float rowbuf[4][292];  // skewed: 256 + 256/8 + pad

  const int w = threadIdx.x >> 6;
  const int l = threadIdx.x & 63;
  const int half = l >> 5;   // edge slot 0/1
  const int li = l & 31;     // 8 channels per lane: [li*8, li*8+8)
  const int h3 = li >> 2;    // head owning these channels
  const int n = blockIdx.x * 4 + w;
  if (n >= N) return;

  const int off = offsets[n];
  const int deg = offsets[n + 1] - off;
  const float* hb = h_lin + li * 8;

  float c0 = 0.f, c1 = 0.f, c2 = 0.f, c3 = 0.f, c4 = 0.f, c5 = 0.f, c6 = 0.f, c7 = 0.f;
  float sw = 0.f;
  int e = 0;
  for (; e + 8 <= deg; e += 8) {
    const int p0 = off + e + half;
    int s0 = csr_src[p0];
    int s1 = csr_src[p0 + 2];
    int s2 = csr_src[p0 + 4];
    int s3 = csr_src[p0 + 6];
    float w0 = ew[(size_t)p0 * 8 + h3];
    float w1 = ew[(size_t)(p0 + 2) * 8 + h3];
    float w2v = ew[(size_t)(p0 + 4) * 8 + h3];
    float w3 = ew[(size_t)(p0 + 6) * 8 + h3];
    const float* r0p = hb + (size_t)s0 * 256;
    const float* r1p = hb + (size_t)s1 * 256;
    const float* r2p = hb + (size_t)s2 * 256;
    const float* r3p = hb + (size_t)s3 * 256;
    float4 r0a = *(const float4*)(r0p), r0b = *(const float4*)(r0p + 4);
    float4 r1a = *(const float4*)(r1p), r1b = *(const float4*)(r1p + 4);
    float4 r2a = *(const float4*)(r2p), r2b = *(const float4*)(r2p + 4);
    float4 r3a = *(const float4*)(r3p), r3b = *(const float4*)(r3p + 4);
    sw += (w0 + w1) + (w2v + w3);
    c0 += w0 * r0a.x + w1 * r1a.x + w2v * r2a.x + w3 * r3a.x;
    c1 += w0 * r0a.y + w1 * r1a.y + w2v * r2a.y + w3 * r3a.y;
    c2 += w0 * r0a.z + w1 * r1a.z + w2v * r2a.z + w3 * r3a.z;
    c3 += w0 * r0a.w + w1 * r1a.w + w2v * r2a.w + w3 * r3a.w;
    c4 += w0 * r0b.x + w1 * r1b.x + w2v * r2b.x + w3 * r3b.x;
    c5 += w0 * r0b.y + w1 * r1b.y + w2v * r2b.y + w3 * r3b.y;
    c6 += w0 * r0b.z + w1 * r1b.z + w2v * r2b.z + w3 * r3b.z;
    c7 += w0 * r0b.w + w1 * r1b.w + w2v * r2b.w + w3 * r3b.w;
  }
  for (; e < deg; e += 2) {
    int ee = e + half;
    if (ee < deg) {
      int p = off + ee;
      int s = csr_src[p];
      float ww = ew[(size_t)p * 8 + h3];
      const float* rp = hb + (size_t)s * 256;
      float4 ra = *(const float4*)(rp), rb = *(const float4*)(rp + 4);
      sw += ww;
      c0 += ww * ra.x; c1 += ww * ra.y; c2 += ww * ra.z; c3 += ww * ra.w;
      c4 += ww * rb.x; c5 += ww * rb.y; c6 += ww * rb.z; c7 += ww * rb.w;
    }
  }
  // cross-half reduce: combine the two edge slots
  c0 += __shfl_xor(c0, 32); c1 += __shfl_xor(c1, 32);
  c2 += __shfl_xor(c2, 32); c3 += __shfl_xor(c3, 32);
  c4 += __shfl_xor(c4, 32); c5 += __shfl_xor(c5, 32);
  c6 += __shfl_xor(c6, 32); c7 += __shfl_xor(c7, 32);
  sw += __shfl_xor(sw, 32);
  const float inv = 1.f / (sw + 1e-16f);

  if (half == 0) {
    float4 ba = *(const float4*)(b1 + li * 8);
    float4 bbv = *(const float4*)(b1 + li * 8 + 4);
    rowbuf[w][RB(li * 8 + 0)] = fmaxf(c0 * inv + ba.x, 0.f);
    rowbuf[w][RB(li * 8 + 1)] = fmaxf(c1 * inv + ba.y, 0.f);
    rowbuf[w][RB(li * 8 + 2)] = fmaxf(c2 * inv + ba.z, 0.f);
    rowbuf[w][RB(li * 8 + 3)] = fmaxf(c3 * inv + ba.w, 0.f);
    rowbuf[w][RB(li * 8 + 4)] = fmaxf(c4 * inv + bbv.x, 0.f);
    rowbuf[w][RB(li * 8 + 5)] = fmaxf(c5 * inv + bbv.y, 0.f);
    rowbuf[w][RB(li * 8 + 6)] = fmaxf(c6 * inv + bbv.z, 0.f);
    rowbuf[w][RB(li * 8 + 7)] = fmaxf(c7 * inv + bbv.w, 0.f);
  }
  asm volatile("s_waitcnt lgkmcnt(0)" ::: "memory");

  // h2[n,o] = sum_cc relu_row[cc] * W2[cc,o]; grp-rotated walk; W2 from global (L1-hot)
  const int o = l & 15;
  const int grp = l >> 4;
  float a2 = 0.f;
#pragma unroll 8
  for (int t = 0; t < 64; ++t) {
    int cc = grp * 64 + ((t + grp * 8) & 63);
    a2 += rowbuf[w][RB(cc)] * W2[cc * 16 + o];
  }
  a2 += __shfl_xor(a2, 16);
  a2 += __shfl_xor(a2, 32);

  if (l < 16) {
    h2[(size_t)n * 16 + l] = a2;
    float ps = a2 * a_src2[l];
    float pd = a2 * a_dst2[l];
    ps += __shfl_xor(ps, 1); pd += __shfl_xor(pd, 1);
    ps += __shfl_xor(ps, 2); pd += __shfl_xor(pd, 2);
    ps += __shfl_xor(ps, 4); pd += __shfl_xor(pd, 4);
    ps += __shfl_xor(ps, 8); pd += __shfl_xor(pd, 8);
    if (l == 0) { als2[n] = ps; ald2[n] = pd; }
  }
}

// ============ GAT layer 2: single-pass aggregation -> x1, g, keys + bucket hist ============
__global__ __launch_bounds__(256) void k_gat2(
    const float* __restrict__ h2, const float* __restrict__ ew2,
    const float* __restrict__ b2, const float* __restrict__ proj_w,
    const float* __restrict__ proj_b, const int* __restrict__ offsets,
    const int* __restrict__ csr_src, float* __restrict__ x1,
    float* __restrict__ g, unsigned long long* __restrict__ keys,
    int* __restrict__ bhist, int N) {
  const int w = threadIdx.x >> 6;
  const int l = threadIdx.x & 63;
  const int n = blockIdx.x * 4 + w;
  if (n >= N) return;
  const int off = offsets[n];
  const int deg = offsets[n + 1] - off;
  const int slot = l >> 4;  // 4 parallel edge slots
  const int c = l & 15;

  float acc = 0.f, sw = 0.f;
  int e0 = 0;
  for (; e0 + 8 <= deg; e0 += 8) {
    int pA = off + e0 + slot;
    int pB = off + e0 + 4 + slot;
    int sA = csr_src[pA];
    int sB = csr_src[pB];
    float wA = ew2[pA];
    float wB = ew2[pB];
    float hA = h2[(size_t)sA * 16 + c];
    float hB = h2[(size_t)sB * 16 + c];
    sw += wA + wB;
    acc += wA * hA + wB * hB;
  }
  for (; e0 < deg; e0 += 4) {
    int e = e0 + slot;
    if (e < deg) {
      int p = off + e;
      int s = csr_src[p];
      float v = ew2[p];
      sw += v;
      acc += v * h2[(size_t)s * 16 + c];
    }
  }
  acc += __shfl_xor(acc, 16); sw += __shfl_xor(sw, 16);
  acc += __shfl_xor(acc, 32); sw += __shfl_xor(sw, 32);
  float x1v = acc / (sw + 1e-16f) + b2[c];

  float pg = x1v * proj_w[c];
  pg += __shfl_xor(pg, 1);
  pg += __shfl_xor(pg, 2);
  pg += __shfl_xor(pg, 4);
  pg += __shfl_xor(pg, 8);
  if (l < 16) x1[(size_t)n * 16 + l] = x1v;
  if (l == 0) {
    float gv = pg + proj_b[0];
    g[n] = gv;
    unsigned u = __float_as_uint(gv);
    u = (u & 0x80000000u) ? ~u : (u | 0x80000000u);
    keys[n] = (((unsigned long long)u) << 32) | (unsigned)n;
    atomicAdd(&bhist[u >> 16], 1);
  }
}

// ============ bucket scatter ============
__global__ __launch_bounds__(256) void k_bscatter(const unsigned long long* __restrict__ keys,
                                                  int* __restrict__ cursor,
                                                  unsigned long long* __restrict__ bkeys, int N) {
  int n = blockIdx.x * 256 + threadIdx.x;
  if (n >= N) return;
  unsigned long long k = keys[n];
  int b = (int)(k >> 48);
  int pos = atomicAdd(&cursor[b], 1);
  bkeys[pos] = k;
}

// ============ exact stable rank within bucket + scatter g*x1 to sorted order ============
__global__ __launch_bounds__(256) void k_brank(const unsigned long long* __restrict__ bkeys,
                                               const int* __restrict__ boffs,
                                               const float* __restrict__ g,
                                               const float* __restrict__ x1,
                                               int* __restrict__ rank,
                                               float* __restrict__ sortedv, int N) {
  int pos = blockIdx.x * 256 + threadIdx.x;
  if (pos >= N) return;
  unsigned long long k = bkeys[pos];
  int b = (int)(k >> 48);
  int lo = boffs[b], hi = boffs[b + 1];
  int r = lo;
  for (int j = lo; j < hi; ++j) r += (bkeys[j] < k) ? 1 : 0;
  int idx = (int)(unsigned)(k & 0xffffffffull);
  rank[idx] = r;
  float gv = g[idx];
#pragma unroll
  for (int c = 0; c < 16; c += 4) {
    float4 v = *(const float4*)(x1 + (size_t)idx * 16 + c);
    float4 o = make_float4(gv * v.x, gv * v.y, gv * v.z, gv * v.w);
    *(float4*)(sortedv + (size_t)r * 16 + c) = o;
  }
}

// ============ conv1d 'same', K=5, 16->16 channels ============
__global__ __launch_bounds__(256) void k_conv(const float* __restrict__ in,
                                              const float* __restrict__ wgt,
                                              const float* __restrict__ bias,
                                              float* __restrict__ out, int N, int relu) {
  __shared__ float s[260][17];
  __shared__ float ws[1280];
  __shared__ float bs[16];
  const int p0 = blockIdx.x * 256;
  for (int i = threadIdx.x; i < 1280; i += 256) ws[i] = wgt[i];
  if (threadIdx.x < 16) bs[threadIdx.x] = bias[threadIdx.x];
  for (int idx = threadIdx.x; idx < 260 * 16; idx += 256) {
    int lp = idx >> 4, c = idx & 15;
    int gp = p0 - 2 + lp;
    s[lp][c] = (gp >= 0 && gp < N) ? in[(size_t)gp * 16 + c] : 0.f;
  }
  __syncthreads();
  const int p = p0 + threadIdx.x;
  if (p >= N) return;
  float acc[16];
#pragma unroll
  for (int o = 0; o < 16; ++o) acc[o] = bs[o];
  for (int k = 0; k < 5; ++k) {
    for (int c = 0; c < 16; ++c) {
      float xv = s[threadIdx.x + k][c];
#pragma unroll
      for (int o = 0; o < 16; ++o) acc[o] += ws[(o * 16 + c) * 5 + k] * xv;
    }
  }
#pragma unroll
  for (int o = 0; o < 16; ++o) {
    float v = acc[o];
    if (relu) v = fmaxf(v, 0.f);
    out[(size_t)p * 16 + o] = v;
  }
}

// ============ final: concat(x1, x2=conv2[rank]) @ lin_w + lin_b -> log_softmax ============
__global__ __launch_bounds__(256) void k_final(
    const float* __restrict__ x1, const float* __restrict__ c2out,
    const int* __restrict__ rank, const float* __restrict__ lin_w,
    const float* __restrict__ lin_b, float* __restrict__ out, int N) {
  __shared__ float lw[512];
  __shared__ float lb[16];
  for (int i = threadIdx.x; i < 512; i += 256) lw[i] = lin_w[i];
  if (threadIdx.x < 16) lb[threadIdx.x] = lin_b[threadIdx.x];
  __syncthreads();
  const int n = blockIdx.x * 256 + threadIdx.x;
  if (n >= N) return;
  float xa[16], xb[16];
  const int r = rank[n];
#pragma unroll
  for (int c = 0; c < 16; c += 4) {
    float4 va = *(const float4*)(x1 + (size_t)n * 16 + c);
    float4 vb = *(const float4*)(c2out + (size_t)r * 16 + c);
    xa[c] = va.x; xa[c + 1] = va.y; xa[c + 2] = va.z; xa[c + 3] = va.w;
    xb[c] = vb.x; xb[c + 1] = vb.y; xb[c + 2] = vb.z; xb[c + 3] = vb.w;
  }
  float z[16];
#pragma unroll
  for (int o = 0; o < 16; ++o) z[o] = lb[o];
#pragma unroll
  for (int c = 0; c < 16; ++c) {
    float va = xa[c], vb = xb[c];
#pragma unroll
    for (int o = 0; o < 16; ++o) z[o] += va * lw[c * 16 + o] + vb * lw[(16 + c) * 16 + o];
  }
  float m = z[0];
#pragma unroll
  for (int o = 1; o < 16; ++o) m = fmaxf(m, z[o]);
  float ssum = 0.f;
#pragma unroll
  for (int o = 0; o < 16; ++o) ssum += expf(z[o] - m);
  float lse = m + logf(ssum);
#pragma unroll
  for (int o = 0; o < 16; ++o) out[(size_t)n * 16 + o] = z[o] - lse;
}

extern "C" void kernel_launch(void* const* d_in, const int* in_sizes, int n_in,
                              void* d_out, int out_size, void* d_ws, size_t ws_size,
                              hipStream_t stream) {
  const float* x = (const float*)d_in[0];
  const int* ei = (const int*)d_in[1];
  const float* W1 = (const float*)d_in[2];
  const float* a_src1 = (const float*)d_in[3];
  const float* a_dst1 = (const float*)d_in[4];
  const float* b1 = (const float*)d_in[5];
  const float* W2 = (const float*)d_in[6];
  const float* a_src2 = (const float*)d_in[7];
  const float* a_dst2 = (const float*)d_in[8];
  const float* b2 = (const float*)d_in[9];
  const float* proj_w = (const float*)d_in[10];
  const float* proj_b = (const float*)d_in[11];
  const float* c1_w = (const float*)d_in[12];
  const float* c1_b = (const float*)d_in[13];
  const float* c2_w = (const float*)d_in[14];
  const float* c2_b = (const float*)d_in[15];
  const float* lin_w = (const float*)d_in[16];
  const float* lin_b = (const float*)d_in[17];
  float* out = (float*)d_out;

  const int N = in_sizes[0] / 256;
  const int E = in_sizes[1] / 2;
  const int Etot = E + N;

  // CSR scan padding: 1024 threads x chunk, chunk multiple of 4
  int chunk = (N + 1023) / 1024;
  chunk = (chunk + 3) & ~3;
  const int Npad = 1024 * chunk;

  char* ws = (char*)d_ws;
  size_t off = 0;
  auto alloc = [&](size_t bytes) -> void* {
    void* p = ws + off;
    off = (off + bytes + 255) & ~(size_t)255;
    return p;
  };
  float* h_lin = (float*)alloc((size_t)N * 256 * 4);
  float* als1 = (float*)alloc((size_t)N * 8 * 4);
  float* ald1 = (float*)alloc((size_t)N * 8 * 4);
  int* counts = (int*)alloc((size_t)Npad * 4);
  int* offsets = (int*)alloc((size_t)(Npad + 1) * 4);
  int* cursor = (int*)alloc((size_t)Npad * 4);
  int* csr_src = (int*)alloc((size_t)Etot * 4);
  int* csr_dst = (int*)alloc((size_t)Etot * 4);
  float* ew = (float*)alloc((size_t)Etot * 8 * 4);
  float* ew2 = (float*)alloc((size_t)Etot * 4);
  float* h2 = (float*)alloc((size_t)N * 16 * 4);
  float* als2 = (float*)alloc((size_t)N * 4);
  float* ald2 = (float*)alloc((size_t)N * 4);
  float* x1 = (float*)alloc((size_t)N * 16 * 4);
  float* gbuf = (float*)alloc((size_t)N * 4);
  unsigned long long* keys = (unsigned long long*)alloc((size_t)N * 8);
  int* bhist = (int*)alloc((size_t)NBUCKET * 4);
  int* boffs = (int*)alloc((size_t)(NBUCKET + 1) * 4);
  int* bcursor = (int*)alloc((size_t)NBUCKET * 4);
  unsigned long long* bkeys = (unsigned long long*)alloc((size_t)N * 8);
  int* rank = (int*)alloc((size_t)N * 4);
  float* sortedv = (float*)alloc((size_t)N * 16 * 4);
  float* c1out = (float*)alloc((size_t)N * 16 * 4);
  float* c2out = (float*)alloc((size_t)N * 16 * 4);
  if (off > ws_size) return;  // fail loudly rather than corrupt memory

  hipMemsetAsync(counts, 0, (size_t)Npad * 4, stream);
  hipMemsetAsync(bhist, 0, (size_t)NBUCKET * 4, stream);

  dim3 gg((N + 127) / 128, 2);
  k_gemm1<<<gg, 256, 0, stream>>>(x, W1, h_lin, N);
  k_al1<<<(N + 3) / 4, 256, 0, stream>>>(h_lin, a_src1, a_dst1, als1, ald1, N);
  k_hist<<<(Etot + 255) / 256, 256, 0, stream>>>(ei, counts, E, N);
  k_scan<<<1, 1024, 0, stream>>>(counts, offsets, cursor, chunk);
  k_scatter_ew<<<(Etot + 255) / 256, 256, 0, stream>>>(ei, als1, ald1, cursor,
                                                       csr_src, csr_dst, ew, E, N);
  k_gat1<<<(N + 3) / 4, 256, 0, stream>>>(h_lin, ew, b1, offsets, csr_src,
                                          W2, a_src2, a_dst2, h2, als2, ald2, N);
  k_ew2<<<(Etot + 255) / 256, 256, 0, stream>>>(csr_src, csr_dst, als2, ald2, ew2, Etot);
  k_gat2<<<(N + 3) / 4, 256, 0, stream>>>(h2, ew2, b2, proj_w, proj_b,
                                          offsets, csr_src, x1, gbuf, keys, bhist, N);
  k_scan<<<1, 1024, 0, stream>>>(bhist, boffs, bcursor, NBUCKET / 1024);
  k_bscatter<<<(N + 255) / 256, 256, 0, stream>>>(keys, bcursor, bkeys, N);
  k_brank<<<(N + 255) / 256, 256, 0, stream>>>(bkeys, boffs, gbuf, x1, rank, sortedv, N);
  k_conv<<<(N + 255) / 256, 256, 0, stream>>>(sortedv, c1_w, c1_b, c1out, N, 1);
  k_conv<<<(N + 255) / 256, 256, 0, stream>>>(c1out, c2_w, c2_b, c2out, N, 0);
  k_final<<<(N + 255) / 256, 256, 0, stream>>>(x1, c2out, rank, lin_w, lin_b, out, N);
}

// Round 10
// 539.446 us; speedup vs baseline: 1.1077x; 1.1077x over previous
//
#include <hip/hip_runtime.h>
#include <math.h>

#define NBUCKET 65536

__device__ __forceinline__ float leakyrelu02(float v) { return v > 0.f ? v : 0.2f * v; }

// ============ GEMM: C[M,256] = A[M,256] @ B[256,256], fp32 ============
// 64x64 tile, lane=row, acc[16]/thread. A via LDS (ds_read_b32, 2-way free);
// B via wave-uniform scalar loads (s_load; readfirstlane-pinned) -> no LDS, no VGPR cost.
__global__ __launch_bounds__(256) void k_gemm1(const float* __restrict__ A,
                                               const float* __restrict__ B,
                                               float* __restrict__ C, int M) {
  __shared__ float As[16][68];
  const int m0 = blockIdx.x * 64;
  const int n0 = blockIdx.y * 64;
  const int tid = threadIdx.x;
  const int l = tid & 63;
  const int wu = __builtin_amdgcn_readfirstlane(tid >> 6);  // wave id 0..3 in SGPR
  const float* __restrict__ Bw = B + n0 + wu * 16;          // uniform pointer

  float acc[16];
#pragma unroll
  for (int j = 0; j < 16; ++j) acc[j] = 0.f;

  const int arow = tid & 63, akk = (tid >> 6) * 4;

  for (int k0 = 0; k0 < 256; k0 += 16) {
    float4 av = make_float4(0.f, 0.f, 0.f, 0.f);
    if (m0 + arow < M) av = *(const float4*)(A + (size_t)(m0 + arow) * 256 + k0 + akk);
    As[akk + 0][arow] = av.x;
    As[akk + 1][arow] = av.y;
    As[akk + 2][arow] = av.z;
    As[akk + 3][arow] = av.w;
    __syncthreads();
#pragma unroll
    for (int kk = 0; kk < 16; ++kk) {
      const float* bp = Bw + (size_t)(k0 + kk) * 256;  // uniform -> s_load
      float4 b0 = *(const float4*)(bp);
      float4 b1 = *(const float4*)(bp + 4);
      float4 b2 = *(const float4*)(bp + 8);
      float4 b3 = *(const float4*)(bp + 12);
      float a = As[kk][l];
      acc[0] += a * b0.x;  acc[1] += a * b0.y;  acc[2] += a * b0.z;  acc[3] += a * b0.w;
      acc[4] += a * b1.x;  acc[5] += a * b1.y;  acc[6] += a * b1.z;  acc[7] += a * b1.w;
      acc[8] += a * b2.x;  acc[9] += a * b2.y;  acc[10] += a * b2.z; acc[11] += a * b2.w;
      acc[12] += a * b3.x; acc[13] += a * b3.y; acc[14] += a * b3.z; acc[15] += a * b3.w;
    }
    __syncthreads();
  }
  const int m = m0 + l;
  if (m < M) {
    float* cp = C + (size_t)m * 256 + n0 + wu * 16;
    *(float4*)(cp + 0) = make_float4(acc[0], acc[1], acc[2], acc[3]);
    *(float4*)(cp + 4) = make_float4(acc[4], acc[5], acc[6], acc[7]);
    *(float4*)(cp + 8) = make_float4(acc[8], acc[9], acc[10], acc[11]);
    *(float4*)(cp + 12) = make_float4(acc[12], acc[13], acc[14], acc[15]);
  }
}

// ============ attention logits for layer 1: wave per node ============
__global__ __launch_bounds__(256) void k_al1(const float* __restrict__ h_lin,
                                             const float* __restrict__ a_src,
                                             const float* __restrict__ a_dst,
                                             float* __restrict__ als,
                                             float* __restrict__ ald, int N) {
  int gid = blockIdx.x * 256 + threadIdx.x;
  int n = gid >> 6;
  int l = threadIdx.x & 63;
  if (n >= N) return;
  float4 h4 = *(const float4*)(h_lin + (size_t)n * 256 + l * 4);
  float4 vs = *(const float4*)(a_src + l * 4);
  float4 vd = *(const float4*)(a_dst + l * 4);
  float ps = h4.x * vs.x + h4.y * vs.y + h4.z * vs.z + h4.w * vs.w;
  float pd = h4.x * vd.x + h4.y * vd.y + h4.z * vd.z + h4.w * vd.w;
  ps += __shfl_xor(ps, 1); pd += __shfl_xor(pd, 1);
  ps += __shfl_xor(ps, 2); pd += __shfl_xor(pd, 2);
  ps += __shfl_xor(ps, 4); pd += __shfl_xor(pd, 4);
  if ((l & 7) == 0) {
    als[(size_t)n * 8 + (l >> 3)] = ps;
    ald[(size_t)n * 8 + (l >> 3)] = pd;
  }
}

// ============ CSR build: per-dst histogram ============
__global__ __launch_bounds__(256) void k_hist(const int* __restrict__ ei,
                                              int* __restrict__ counts, int E, int N) {
  int e = blockIdx.x * 256 + threadIdx.x;
  if (e >= E + N) return;
  int d = (e < E) ? ei[E + e] : (e - E);
  atomicAdd(&counts[d], 1);
}

// scan over Npad = 1024*chunk entries (chunk multiple of 4, counts padded+zeroed)
__global__ __launch_bounds__(1024) void k_scan(const int* __restrict__ counts,
                                               int* __restrict__ offsets,
                                               int* __restrict__ cursor, int chunk) {
  __shared__ int part[1024];
  const int t = threadIdx.x;
  const int base = t * chunk;
  int ssum = 0;
  for (int i = 0; i < chunk; i += 4) {
    int4 v = *(const int4*)(counts + base + i);
    ssum += v.x + v.y + v.z + v.w;
  }
  part[t] = ssum;
  __syncthreads();
  for (int d = 1; d < 1024; d <<= 1) {
    int v = (t >= d) ? part[t - d] : 0;
    __syncthreads();
    part[t] += v;
    __syncthreads();
  }
  int run = (t == 0) ? 0 : part[t - 1];
  for (int i = 0; i < chunk; i += 4) {
    int4 v = *(const int4*)(counts + base + i);
    int4 o;
    o.x = run; run += v.x;
    o.y = run; run += v.y;
    o.z = run; run += v.z;
    o.w = run; run += v.w;
    *(int4*)(offsets + base + i) = o;
    if (cursor) *(int4*)(cursor + base + i) = o;
  }
  if (t == 1023) offsets[1024 * chunk] = run;
}

// ============ scatter edges + precompute layer-1 edge weights ============
__global__ __launch_bounds__(256) void k_scatter_ew(
    const int* __restrict__ ei, const float* __restrict__ als1,
    const float* __restrict__ ald1, int* __restrict__ cursor,
    int* __restrict__ csr_src, int* __restrict__ csr_dst,
    float* __restrict__ ew, int E, int N) {
  int e = blockIdx.x * 256 + threadIdx.x;
  if (e >= E + N) return;
  int d, s;
  if (e < E) { d = ei[E + e]; s = ei[e]; }
  else { d = e - E; s = d; }
  int pos = atomicAdd(&cursor[d], 1);
  csr_src[pos] = s;
  csr_dst[pos] = d;
  float4 as0 = *(const float4*)(als1 + (size_t)s * 8);
  float4 as1 = *(const float4*)(als1 + (size_t)s * 8 + 4);
  float4 ad0 = *(const float4*)(ald1 + (size_t)d * 8);
  float4 ad1 = *(const float4*)(ald1 + (size_t)d * 8 + 4);
  float4 w0, w1;
  w0.x = expf(leakyrelu02(as0.x + ad0.x));
  w0.y = expf(leakyrelu02(as0.y + ad0.y));
  w0.z = expf(leakyrelu02(as0.z + ad0.z));
  w0.w = expf(leakyrelu02(as0.w + ad0.w));
  w1.x = expf(leakyrelu02(as1.x + ad1.x));
  w1.y = expf(leakyrelu02(as1.y + ad1.y));
  w1.z = expf(leakyrelu02(as1.z + ad1.z));
  w1.w = expf(leakyrelu02(as1.w + ad1.w));
  *(float4*)(ew + (size_t)pos * 8) = w0;
  *(float4*)(ew + (size_t)pos * 8 + 4) = w1;
}

// ============ layer-2 edge weights, edge-parallel ============
__global__ __launch_bounds__(256) void k_ew2(const int* __restrict__ csr_src,
                                             const int* __restrict__ csr_dst,
                                             const float* __restrict__ als2,
                                             const float* __restrict__ ald2,
                                             float* __restrict__ ew2, int Etot) {
  int t = blockIdx.x * 256 + threadIdx.x;
  if (t >= Etot) return;
  ew2[t] = expf(leakyrelu02(als2[csr_src[t]] + ald2[csr_dst[t]]));
}

// rowbuf skew: channel i stored at i + (i>>3)  (kills 8-way write conflicts)
#define RB(i) ((i) + ((i) >> 3))

// ============ GAT layer 1: 2-edge x 32-lane split, 8 rows in flight +
// fused (relu row) @ W2 (W2 direct from global/L1) -> h2, al2 ============
__global__ __launch_bounds__(256) void k_gat1(
    const float* __restrict__ h_lin, const float* __restrict__ ew,
    const float* __restrict__ b1, const int* __restrict__ offsets,
    const int* __restrict__ csr_src, const float* __restrict__ W2,
    const float* __restrict__ a_src2, const float* __restrict__ a_dst2,
    float* __restrict__ h2, float* __restrict__ als2, float* __restrict__ ald2, int N) {
  __shared__ float rowbuf[4][292];  // skewed: 256 + 256/8 + pad

  const int w = threadIdx.x >> 6;
  const int l = threadIdx.x & 63;
  const int half = l >> 5;   // edge slot 0/1
  const int li = l & 31;     // 8 channels per lane: [li*8, li*8+8)
  const int h3 = li >> 2;    // head owning these channels
  const int n = blockIdx.x * 4 + w;
  if (n >= N) return;

  const int off = offsets[n];
  const int deg = offsets[n + 1] - off;
  const float* hb = h_lin + li * 8;

  float c0 = 0.f, c1 = 0.f, c2 = 0.f, c3 = 0.f, c4 = 0.f, c5 = 0.f, c6 = 0.f, c7 = 0.f;
  float sw = 0.f;
  int e = 0;
  for (; e + 8 <= deg; e += 8) {
    const int p0 = off + e + half;
    int s0 = csr_src[p0];
    int s1 = csr_src[p0 + 2];
    int s2 = csr_src[p0 + 4];
    int s3 = csr_src[p0 + 6];
    float w0 = ew[(size_t)p0 * 8 + h3];
    float w1 = ew[(size_t)(p0 + 2) * 8 + h3];
    float w2v = ew[(size_t)(p0 + 4) * 8 + h3];
    float w3 = ew[(size_t)(p0 + 6) * 8 + h3];
    const float* r0p = hb + (size_t)s0 * 256;
    const float* r1p = hb + (size_t)s1 * 256;
    const float* r2p = hb + (size_t)s2 * 256;
    const float* r3p = hb + (size_t)s3 * 256;
    float4 r0a = *(const float4*)(r0p), r0b = *(const float4*)(r0p + 4);
    float4 r1a = *(const float4*)(r1p), r1b = *(const float4*)(r1p + 4);
    float4 r2a = *(const float4*)(r2p), r2b = *(const float4*)(r2p + 4);
    float4 r3a = *(const float4*)(r3p), r3b = *(const float4*)(r3p + 4);
    sw += (w0 + w1) + (w2v + w3);
    c0 += w0 * r0a.x + w1 * r1a.x + w2v * r2a.x + w3 * r3a.x;
    c1 += w0 * r0a.y + w1 * r1a.y + w2v * r2a.y + w3 * r3a.y;
    c2 += w0 * r0a.z + w1 * r1a.z + w2v * r2a.z + w3 * r3a.z;
    c3 += w0 * r0a.w + w1 * r1a.w + w2v * r2a.w + w3 * r3a.w;
    c4 += w0 * r0b.x + w1 * r1b.x + w2v * r2b.x + w3 * r3b.x;
    c5 += w0 * r0b.y + w1 * r1b.y + w2v * r2b.y + w3 * r3b.y;
    c6 += w0 * r0b.z + w1 * r1b.z + w2v * r2b.z + w3 * r3b.z;
    c7 += w0 * r0b.w + w1 * r1b.w + w2v * r2b.w + w3 * r3b.w;
  }
  for (; e < deg; e += 2) {
    int ee = e + half;
    if (ee < deg) {
      int p = off + ee;
      int s = csr_src[p];
      float ww = ew[(size_t)p * 8 + h3];
      const float* rp = hb + (size_t)s * 256;
      float4 ra = *(const float4*)(rp), rb = *(const float4*)(rp + 4);
      sw += ww;
      c0 += ww * ra.x; c1 += ww * ra.y; c2 += ww * ra.z; c3 += ww * ra.w;
      c4 += ww * rb.x; c5 += ww * rb.y; c6 += ww * rb.z; c7 += ww * rb.w;
    }
  }
  // cross-half reduce: combine the two edge slots
  c0 += __shfl_xor(c0, 32); c1 += __shfl_xor(c1, 32);
  c2 += __shfl_xor(c2, 32); c3 += __shfl_xor(c3, 32);
  c4 += __shfl_xor(c4, 32); c5 += __shfl_xor(c5, 32);
  c6 += __shfl_xor(c6, 32); c7 += __shfl_xor(c7, 32);
  sw += __shfl_xor(sw, 32);
  const float inv = 1.f / (sw + 1e-16f);

  if (half == 0) {
    float4 ba = *(const float4*)(b1 + li * 8);
    float4 bbv = *(const float4*)(b1 + li * 8 + 4);
    rowbuf[w][RB(li * 8 + 0)] = fmaxf(c0 * inv + ba.x, 0.f);
    rowbuf[w][RB(li * 8 + 1)] = fmaxf(c1 * inv + ba.y, 0.f);
    rowbuf[w][RB(li * 8 + 2)] = fmaxf(c2 * inv + ba.z, 0.f);
    rowbuf[w][RB(li * 8 + 3)] = fmaxf(c3 * inv + ba.w, 0.f);
    rowbuf[w][RB(li * 8 + 4)] = fmaxf(c4 * inv + bbv.x, 0.f);
    rowbuf[w][RB(li * 8 + 5)] = fmaxf(c5 * inv + bbv.y, 0.f);
    rowbuf[w][RB(li * 8 + 6)] = fmaxf(c6 * inv + bbv.z, 0.f);
    rowbuf[w][RB(li * 8 + 7)] = fmaxf(c7 * inv + bbv.w, 0.f);
  }
  asm volatile("s_waitcnt lgkmcnt(0)" ::: "memory");

  // h2[n,o] = sum_cc relu_row[cc] * W2[cc,o]; grp-rotated walk; W2 from global (L1-hot)
  const int o = l & 15;
  const int grp = l >> 4;
  float a2 = 0.f;
#pragma unroll 8
  for (int t = 0; t < 64; ++t) {
    int cc = grp * 64 + ((t + grp * 8) & 63);
    a2 += rowbuf[w][RB(cc)] * W2[cc * 16 + o];
  }
  a2 += __shfl_xor(a2, 16);
  a2 += __shfl_xor(a2, 32);

  if (l < 16) {
    h2[(size_t)n * 16 + l] = a2;
    float ps = a2 * a_src2[l];
    float pd = a2 * a_dst2[l];
    ps += __shfl_xor(ps, 1); pd += __shfl_xor(pd, 1);
    ps += __shfl_xor(ps, 2); pd += __shfl_xor(pd, 2);
    ps += __shfl_xor(ps, 4); pd += __shfl_xor(pd, 4);
    ps += __shfl_xor(ps, 8); pd += __shfl_xor(pd, 8);
    if (l == 0) { als2[n] = ps; ald2[n] = pd; }
  }
}

// ============ GAT layer 2: single-pass aggregation -> x1, g, keys + bucket hist ============
__global__ __launch_bounds__(256) void k_gat2(
    const float* __restrict__ h2, const float* __restrict__ ew2,
    const float* __restrict__ b2, const float* __restrict__ proj_w,
    const float* __restrict__ proj_b, const int* __restrict__ offsets,
    const int* __restrict__ csr_src, float* __restrict__ x1,
    float* __restrict__ g, unsigned long long* __restrict__ keys,
    int* __restrict__ bhist, int N) {
  const int w = threadIdx.x >> 6;
  const int l = threadIdx.x & 63;
  const int n = blockIdx.x * 4 + w;
  if (n >= N) return;
  const int off = offsets[n];
  const int deg = offsets[n + 1] - off;
  const int slot = l >> 4;  // 4 parallel edge slots
  const int c = l & 15;

  float acc = 0.f, sw = 0.f;
  int e0 = 0;
  for (; e0 + 8 <= deg; e0 += 8) {
    int pA = off + e0 + slot;
    int pB = off + e0 + 4 + slot;
    int sA = csr_src[pA];
    int sB = csr_src[pB];
    float wA = ew2[pA];
    float wB = ew2[pB];
    float hA = h2[(size_t)sA * 16 + c];
    float hB = h2[(size_t)sB * 16 + c];
    sw += wA + wB;
    acc += wA * hA + wB * hB;
  }
  for (; e0 < deg; e0 += 4) {
    int e = e0 + slot;
    if (e < deg) {
      int p = off + e;
      int s = csr_src[p];
      float v = ew2[p];
      sw += v;
      acc += v * h2[(size_t)s * 16 + c];
    }
  }
  acc += __shfl_xor(acc, 16); sw += __shfl_xor(sw, 16);
  acc += __shfl_xor(acc, 32); sw += __shfl_xor(sw, 32);
  float x1v = acc / (sw + 1e-16f) + b2[c];

  float pg = x1v * proj_w[c];
  pg += __shfl_xor(pg, 1);
  pg += __shfl_xor(pg, 2);
  pg += __shfl_xor(pg, 4);
  pg += __shfl_xor(pg, 8);
  if (l < 16) x1[(size_t)n * 16 + l] = x1v;
  if (l == 0) {
    float gv = pg + proj_b[0];
    g[n] = gv;
    unsigned u = __float_as_uint(gv);
    u = (u & 0x80000000u) ? ~u : (u | 0x80000000u);
    keys[n] = (((unsigned long long)u) << 32) | (unsigned)n;
    atomicAdd(&bhist[u >> 16], 1);
  }
}

// ============ bucket scatter ============
__global__ __launch_bounds__(256) void k_bscatter(const unsigned long long* __restrict__ keys,
                                                  int* __restrict__ cursor,
                                                  unsigned long long* __restrict__ bkeys, int N) {
  int n = blockIdx.x * 256 + threadIdx.x;
  if (n >= N) return;
  unsigned long long k = keys[n];
  int b = (int)(k >> 48);
  int pos = atomicAdd(&cursor[b], 1);
  bkeys[pos] = k;
}

// ============ exact stable rank within bucket + scatter g*x1 to sorted order ============
__global__ __launch_bounds__(256) void k_brank(const unsigned long long* __restrict__ bkeys,
                                               const int* __restrict__ boffs,
                                               const float* __restrict__ g,
                                               const float* __restrict__ x1,
                                               int* __restrict__ rank,
                                               float* __restrict__ sortedv, int N) {
  int pos = blockIdx.x * 256 + threadIdx.x;
  if (pos >= N) return;
  unsigned long long k = bkeys[pos];
  int b = (int)(k >> 48);
  int lo = boffs[b], hi = boffs[b + 1];
  int r = lo;
  for (int j = lo; j < hi; ++j) r += (bkeys[j] < k) ? 1 : 0;
  int idx = (int)(unsigned)(k & 0xffffffffull);
  rank[idx] = r;
  float gv = g[idx];
#pragma unroll
  for (int c = 0; c < 16; c += 4) {
    float4 v = *(const float4*)(x1 + (size_t)idx * 16 + c);
    float4 o = make_float4(gv * v.x, gv * v.y, gv * v.z, gv * v.w);
    *(float4*)(sortedv + (size_t)r * 16 + c) = o;
  }
}

// ============ conv1d 'same', K=5, 16->16 channels ============
__global__ __launch_bounds__(256) void k_conv(const float* __restrict__ in,
                                              const float* __restrict__ wgt,
                                              const float* __restrict__ bias,
                                              float* __restrict__ out, int N, int relu) {
  __shared__ float s[260][17];
  __shared__ float ws[1280];
  __shared__ float bs[16];
  const int p0 = blockIdx.x * 256;
  for (int i = threadIdx.x; i < 1280; i += 256) ws[i] = wgt[i];
  if (threadIdx.x < 16) bs[threadIdx.x] = bias[threadIdx.x];
  for (int idx = threadIdx.x; idx < 260 * 16; idx += 256) {
    int lp = idx >> 4, c = idx & 15;
    int gp = p0 - 2 + lp;
    s[lp][c] = (gp >= 0 && gp < N) ? in[(size_t)gp * 16 + c] : 0.f;
  }
  __syncthreads();
  const int p = p0 + threadIdx.x;
  if (p >= N) return;
  float acc[16];
#pragma unroll
  for (int o = 0; o < 16; ++o) acc[o] = bs[o];
  for (int k = 0; k < 5; ++k) {
    for (int c = 0; c < 16; ++c) {
      float xv = s[threadIdx.x + k][c];
#pragma unroll
      for (int o = 0; o < 16; ++o) acc[o] += ws[(o * 16 + c) * 5 + k] * xv;
    }
  }
#pragma unroll
  for (int o = 0; o < 16; ++o) {
    float v = acc[o];
    if (relu) v = fmaxf(v, 0.f);
    out[(size_t)p * 16 + o] = v;
  }
}

// ============ final: concat(x1, x2=conv2[rank]) @ lin_w + lin_b -> log_softmax ============
__global__ __launch_bounds__(256) void k_final(
    const float* __restrict__ x1, const float* __restrict__ c2out,
    const int* __restrict__ rank, const float* __restrict__ lin_w,
    const float* __restrict__ lin_b, float* __restrict__ out, int N) {
  __shared__ float lw[512];
  __shared__ float lb[16];
  for (int i = threadIdx.x; i < 512; i += 256) lw[i] = lin_w[i];
  if (threadIdx.x < 16) lb[threadIdx.x] = lin_b[threadIdx.x];
  __syncthreads();
  const int n = blockIdx.x * 256 + threadIdx.x;
  if (n >= N) return;
  float xa[16], xb[16];
  const int r = rank[n];
#pragma unroll
  for (int c = 0; c < 16; c += 4) {
    float4 va = *(const float4*)(x1 + (size_t)n * 16 + c);
    float4 vb = *(const float4*)(c2out + (size_t)r * 16 + c);
    xa[c] = va.x; xa[c + 1] = va.y; xa[c + 2] = va.z; xa[c + 3] = va.w;
    xb[c] = vb.x; xb[c + 1] = vb.y; xb[c + 2] = vb.z; xb[c + 3] = vb.w;
  }
  float z[16];
#pragma unroll
  for (int o = 0; o < 16; ++o) z[o] = lb[o];
#pragma unroll
  for (int c = 0; c < 16; ++c) {
    float va = xa[c], vb = xb[c];
#pragma unroll
    for (int o = 0; o < 16; ++o) z[o] += va * lw[c * 16 + o] + vb * lw[(16 + c) * 16 + o];
  }
  float m = z[0];
#pragma unroll
  for (int o = 1; o < 16; ++o) m = fmaxf(m, z[o]);
  float ssum = 0.f;
#pragma unroll
  for (int o = 0; o < 16; ++o) ssum += expf(z[o] - m);
  float lse = m + logf(ssum);
#pragma unroll
  for (int o = 0; o < 16; ++o) out[(size_t)n * 16 + o] = z[o] - lse;
}

extern "C" void kernel_launch(void* const* d_in, const int* in_sizes, int n_in,
                              void* d_out, int out_size, void* d_ws, size_t ws_size,
                              hipStream_t stream) {
  const float* x = (const float*)d_in[0];
  const int* ei = (const int*)d_in[1];
  const float* W1 = (const float*)d_in[2];
  const float* a_src1 = (const float*)d_in[3];
  const float* a_dst1 = (const float*)d_in[4];
  const float* b1 = (const float*)d_in[5];
  const float* W2 = (const float*)d_in[6];
  const float* a_src2 = (const float*)d_in[7];
  const float* a_dst2 = (const float*)d_in[8];
  const float* b2 = (const float*)d_in[9];
  const float* proj_w = (const float*)d_in[10];
  const float* proj_b = (const float*)d_in[11];
  const float* c1_w = (const float*)d_in[12];
  const float* c1_b = (const float*)d_in[13];
  const float* c2_w = (const float*)d_in[14];
  const float* c2_b = (const float*)d_in[15];
  const float* lin_w = (const float*)d_in[16];
  const float* lin_b = (const float*)d_in[17];
  float* out = (float*)d_out;

  const int N = in_sizes[0] / 256;
  const int E = in_sizes[1] / 2;
  const int Etot = E + N;

  // CSR scan padding: 1024 threads x chunk, chunk multiple of 4
  int chunk = (N + 1023) / 1024;
  chunk = (chunk + 3) & ~3;
  const int Npad = 1024 * chunk;

  char* ws = (char*)d_ws;
  size_t off = 0;
  auto alloc = [&](size_t bytes) -> void* {
    void* p = ws + off;
    off = (off + bytes + 255) & ~(size_t)255;
    return p;
  };
  float* h_lin = (float*)alloc((size_t)N * 256 * 4);
  float* als1 = (float*)alloc((size_t)N * 8 * 4);
  float* ald1 = (float*)alloc((size_t)N * 8 * 4);
  int* counts = (int*)alloc((size_t)Npad * 4);
  int* offsets = (int*)alloc((size_t)(Npad + 1) * 4);
  int* cursor = (int*)alloc((size_t)Npad * 4);
  int* csr_src = (int*)alloc((size_t)Etot * 4);
  int* csr_dst = (int*)alloc((size_t)Etot * 4);
  float* ew = (float*)alloc((size_t)Etot * 8 * 4);
  float* ew2 = (float*)alloc((size_t)Etot * 4);
  float* h2 = (float*)alloc((size_t)N * 16 * 4);
  float* als2 = (float*)alloc((size_t)N * 4);
  float* ald2 = (float*)alloc((size_t)N * 4);
  float* x1 = (float*)alloc((size_t)N * 16 * 4);
  float* gbuf = (float*)alloc((size_t)N * 4);
  unsigned long long* keys = (unsigned long long*)alloc((size_t)N * 8);
  int* bhist = (int*)alloc((size_t)NBUCKET * 4);
  int* boffs = (int*)alloc((size_t)(NBUCKET + 1) * 4);
  int* bcursor = (int*)alloc((size_t)NBUCKET * 4);
  unsigned long long* bkeys = (unsigned long long*)alloc((size_t)N * 8);
  int* rank = (int*)alloc((size_t)N * 4);
  float* sortedv = (float*)alloc((size_t)N * 16 * 4);
  float* c1out = (float*)alloc((size_t)N * 16 * 4);
  float* c2out = (float*)alloc((size_t)N * 16 * 4);
  if (off > ws_size) return;  // fail loudly rather than corrupt memory

  hipMemsetAsync(counts, 0, (size_t)Npad * 4, stream);
  hipMemsetAsync(bhist, 0, (size_t)NBUCKET * 4, stream);

  dim3 gg((N + 63) / 64, 4);
  k_gemm1<<<gg, 256, 0, stream>>>(x, W1, h_lin, N);
  k_al1<<<(N + 3) / 4, 256, 0, stream>>>(h_lin, a_src1, a_dst1, als1, ald1, N);
  k_hist<<<(Etot + 255) / 256, 256, 0, stream>>>(ei, counts, E, N);
  k_scan<<<1, 1024, 0, stream>>>(counts, offsets, cursor, chunk);
  k_scatter_ew<<<(Etot + 255) / 256, 256, 0, stream>>>(ei, als1, ald1, cursor,
                                                       csr_src, csr_dst, ew, E, N);
  k_gat1<<<(N + 3) / 4, 256, 0, stream>>>(h_lin, ew, b1, offsets, csr_src,
                                          W2, a_src2, a_dst2, h2, als2, ald2, N);
  k_ew2<<<(Etot + 255) / 256, 256, 0, stream>>>(csr_src, csr_dst, als2, ald2, ew2, Etot);
  k_gat2<<<(N + 3) / 4, 256, 0, stream>>>(h2, ew2, b2, proj_w, proj_b,
                                          offsets, csr_src, x1, gbuf, keys, bhist, N);
  k_scan<<<1, 1024, 0, stream>>>(bhist, boffs, bcursor, NBUCKET / 1024);
  k_bscatter<<<(N + 255) / 256, 256, 0, stream>>>(keys, bcursor, bkeys, N);
  k_brank<<<(N + 255) / 256, 256, 0, stream>>>(bkeys, boffs, gbuf, x1, rank, sortedv, N);
  k_conv<<<(N + 255) / 256, 256, 0, stream>>>(sortedv, c1_w, c1_b, c1out, N, 1);
  k_conv<<<(N + 255) / 256, 256, 0, stream>>>(c1out, c2_w, c2_b, c2out, N, 0);
  k_final<<<(N + 255) / 256, 256, 0, stream>>>(x1, c2out, rank, lin_w, lin_b, out, N);
}

// Round 11
// 532.580 us; speedup vs baseline: 1.1220x; 1.0129x over previous
//
#include <hip/hip_runtime.h>
#include <math.h>

#define NBUCKET 65536

__device__ __forceinline__ float leakyrelu02(float v) { return v > 0.f ? v : 0.2f * v; }

// ============ GEMM: C[M,256] = A[M,256] @ B[256,256], fp32 + fused al1 ============
// 64x64 tile, lane=row, acc[16]/thread. A via LDS; B via wave-uniform scalar loads.
// Epilogue: per-head dots with a_src1/a_dst1 (block covers heads 2by,2by+1 exactly).
__global__ __launch_bounds__(256) void k_gemm1(const float* __restrict__ A,
                                               const float* __restrict__ B,
                                               float* __restrict__ C,
                                               const float* __restrict__ a_src,
                                               const float* __restrict__ a_dst,
                                               float* __restrict__ als,
                                               float* __restrict__ ald, int M) {
  __shared__ float As[16][68];
  __shared__ float pS[64][4];
  __shared__ float pD[64][4];
  const int m0 = blockIdx.x * 64;
  const int n0 = blockIdx.y * 64;
  const int tid = threadIdx.x;
  const int l = tid & 63;
  const int wu = __builtin_amdgcn_readfirstlane(tid >> 6);  // wave id 0..3 in SGPR
  const float* __restrict__ Bw = B + n0 + wu * 16;          // uniform pointer

  float acc[16];
#pragma unroll
  for (int j = 0; j < 16; ++j) acc[j] = 0.f;

  const int arow = tid & 63, akk = (tid >> 6) * 4;

  for (int k0 = 0; k0 < 256; k0 += 16) {
    float4 av = make_float4(0.f, 0.f, 0.f, 0.f);
    if (m0 + arow < M) av = *(const float4*)(A + (size_t)(m0 + arow) * 256 + k0 + akk);
    As[akk + 0][arow] = av.x;
    As[akk + 1][arow] = av.y;
    As[akk + 2][arow] = av.z;
    As[akk + 3][arow] = av.w;
    __syncthreads();
#pragma unroll
    for (int kk = 0; kk < 16; ++kk) {
      const float* bp = Bw + (size_t)(k0 + kk) * 256;  // uniform -> s_load
      float4 b0 = *(const float4*)(bp);
      float4 b1 = *(const float4*)(bp + 4);
      float4 b2 = *(const float4*)(bp + 8);
      float4 b3 = *(const float4*)(bp + 12);
      float a = As[kk][l];
      acc[0] += a * b0.x;  acc[1] += a * b0.y;  acc[2] += a * b0.z;  acc[3] += a * b0.w;
      acc[4] += a * b1.x;  acc[5] += a * b1.y;  acc[6] += a * b1.z;  acc[7] += a * b1.w;
      acc[8] += a * b2.x;  acc[9] += a * b2.y;  acc[10] += a * b2.z; acc[11] += a * b2.w;
      acc[12] += a * b3.x; acc[13] += a * b3.y; acc[14] += a * b3.z; acc[15] += a * b3.w;
    }
    __syncthreads();
  }
  const int m = m0 + l;
  if (m < M) {
    float* cp = C + (size_t)m * 256 + n0 + wu * 16;
    *(float4*)(cp + 0) = make_float4(acc[0], acc[1], acc[2], acc[3]);
    *(float4*)(cp + 4) = make_float4(acc[4], acc[5], acc[6], acc[7]);
    *(float4*)(cp + 8) = make_float4(acc[8], acc[9], acc[10], acc[11]);
    *(float4*)(cp + 12) = make_float4(acc[12], acc[13], acc[14], acc[15]);
  }

  // fused al1: this block's cols n0..n0+63 = heads hseg, hseg+1 (complete)
  const int hseg = n0 >> 5;                 // = 2*blockIdx.y
  const int aoff = (hseg + (wu >> 1)) * 32 + (wu & 1) * 16;
  float ps = 0.f, pd = 0.f;
#pragma unroll
  for (int j = 0; j < 16; ++j) {
    ps += acc[j] * a_src[aoff + j];
    pd += acc[j] * a_dst[aoff + j];
  }
  pS[l][wu] = ps;
  pD[l][wu] = pd;
  __syncthreads();
  if (tid < 128) {
    int row = tid & 63, hp = tid >> 6;
    int mm = m0 + row;
    if (mm < M) {
      als[(size_t)mm * 8 + hseg + hp] = pS[row][hp * 2] + pS[row][hp * 2 + 1];
      ald[(size_t)mm * 8 + hseg + hp] = pD[row][hp * 2] + pD[row][hp * 2 + 1];
    }
  }
}

// ============ CSR build: per-dst histogram ============
__global__ __launch_bounds__(256) void k_hist(const int* __restrict__ ei,
                                              int* __restrict__ counts, int E, int N) {
  int e = blockIdx.x * 256 + threadIdx.x;
  if (e >= E + N) return;
  int d = (e < E) ? ei[E + e] : (e - E);
  atomicAdd(&counts[d], 1);
}

// scan over Npad = 1024*chunk entries (chunk multiple of 4, counts padded+zeroed)
__global__ __launch_bounds__(1024) void k_scan(const int* __restrict__ counts,
                                               int* __restrict__ offsets,
                                               int* __restrict__ cursor, int chunk) {
  __shared__ int part[1024];
  const int t = threadIdx.x;
  const int base = t * chunk;
  int ssum = 0;
  for (int i = 0; i < chunk; i += 4) {
    int4 v = *(const int4*)(counts + base + i);
    ssum += v.x + v.y + v.z + v.w;
  }
  part[t] = ssum;
  __syncthreads();
  for (int d = 1; d < 1024; d <<= 1) {
    int v = (t >= d) ? part[t - d] : 0;
    __syncthreads();
    part[t] += v;
    __syncthreads();
  }
  int run = (t == 0) ? 0 : part[t - 1];
  for (int i = 0; i < chunk; i += 4) {
    int4 v = *(const int4*)(counts + base + i);
    int4 o;
    o.x = run; run += v.x;
    o.y = run; run += v.y;
    o.z = run; run += v.z;
    o.w = run; run += v.w;
    *(int4*)(offsets + base + i) = o;
    if (cursor) *(int4*)(cursor + base + i) = o;
  }
  if (t == 1023) offsets[1024 * chunk] = run;
}

// ============ scatter edges + precompute layer-1 edge weights ============
__global__ __launch_bounds__(256) void k_scatter_ew(
    const int* __restrict__ ei, const float* __restrict__ als1,
    const float* __restrict__ ald1, int* __restrict__ cursor,
    int* __restrict__ csr_src, float* __restrict__ ew, int E, int N) {
  int e = blockIdx.x * 256 + threadIdx.x;
  if (e >= E + N) return;
  int d, s;
  if (e < E) { d = ei[E + e]; s = ei[e]; }
  else { d = e - E; s = d; }
  int pos = atomicAdd(&cursor[d], 1);
  csr_src[pos] = s;
  float4 as0 = *(const float4*)(als1 + (size_t)s * 8);
  float4 as1 = *(const float4*)(als1 + (size_t)s * 8 + 4);
  float4 ad0 = *(const float4*)(ald1 + (size_t)d * 8);
  float4 ad1 = *(const float4*)(ald1 + (size_t)d * 8 + 4);
  float4 w0, w1;
  w0.x = expf(leakyrelu02(as0.x + ad0.x));
  w0.y = expf(leakyrelu02(as0.y + ad0.y));
  w0.z = expf(leakyrelu02(as0.z + ad0.z));
  w0.w = expf(leakyrelu02(as0.w + ad0.w));
  w1.x = expf(leakyrelu02(as1.x + ad1.x));
  w1.y = expf(leakyrelu02(as1.y + ad1.y));
  w1.z = expf(leakyrelu02(as1.z + ad1.z));
  w1.w = expf(leakyrelu02(as1.w + ad1.w));
  *(float4*)(ew + (size_t)pos * 8) = w0;
  *(float4*)(ew + (size_t)pos * 8 + 4) = w1;
}

// rowbuf skew: channel i stored at i + (i>>3)  (kills 8-way write conflicts)
#define RB(i) ((i) + ((i) >> 3))

// ============ GAT layer 1: 2-edge x 32-lane split, 8 rows in flight +
// fused (relu row) @ W2 (W2 direct from global/L1) -> h2, al2 ============
__global__ __launch_bounds__(256) void k_gat1(
    const float* __restrict__ h_lin, const float* __restrict__ ew,
    const float* __restrict__ b1, const int* __restrict__ offsets,
    const int* __restrict__ csr_src, const float* __restrict__ W2,
    const float* __restrict__ a_src2, const float* __restrict__ a_dst2,
    float* __restrict__ h2, float* __restrict__ als2, float* __restrict__ ald2, int N) {
  __shared__ float rowbuf[4][292];  // skewed: 256 + 256/8 + pad

  const int w = threadIdx.x >> 6;
  const int l = threadIdx.x & 63;
  const int half = l >> 5;   // edge slot 0/1
  const int li = l & 31;     // 8 channels per lane: [li*8, li*8+8)
  const int h3 = li >> 2;    // head owning these channels
  const int n = blockIdx.x * 4 + w;
  if (n >= N) return;

  const int off = offsets[n];
  const int deg = offsets[n + 1] - off;
  const float* hb = h_lin + li * 8;

  float c0 = 0.f, c1 = 0.f, c2 = 0.f, c3 = 0.f, c4 = 0.f, c5 = 0.f, c6 = 0.f, c7 = 0.f;
  float sw = 0.f;
  int e = 0;
  for (; e + 8 <= deg; e += 8) {
    const int p0 = off + e + half;
    int s0 = csr_src[p0];
    int s1 = csr_src[p0 + 2];
    int s2 = csr_src[p0 + 4];
    int s3 = csr_src[p0 + 6];
    float w0 = ew[(size_t)p0 * 8 + h3];
    float w1 = ew[(size_t)(p0 + 2) * 8 + h3];
    float w2v = ew[(size_t)(p0 + 4) * 8 + h3];
    float w3 = ew[(size_t)(p0 + 6) * 8 + h3];
    const float* r0p = hb + (size_t)s0 * 256;
    const float* r1p = hb + (size_t)s1 * 256;
    const float* r2p = hb + (size_t)s2 * 256;
    const float* r3p = hb + (size_t)s3 * 256;
    float4 r0a = *(const float4*)(r0p), r0b = *(const float4*)(r0p + 4);
    float4 r1a = *(const float4*)(r1p), r1b = *(const float4*)(r1p + 4);
    float4 r2a = *(const float4*)(r2p), r2b = *(const float4*)(r2p + 4);
    float4 r3a = *(const float4*)(r3p), r3b = *(const float4*)(r3p + 4);
    sw += (w0 + w1) + (w2v + w3);
    c0 += w0 * r0a.x + w1 * r1a.x + w2v * r2a.x + w3 * r3a.x;
    c1 += w0 * r0a.y + w1 * r1a.y + w2v * r2a.y + w3 * r3a.y;
    c2 += w0 * r0a.z + w1 * r1a.z + w2v * r2a.z + w3 * r3a.z;
    c3 += w0 * r0a.w + w1 * r1a.w + w2v * r2a.w + w3 * r3a.w;
    c4 += w0 * r0b.x + w1 * r1b.x + w2v * r2b.x + w3 * r3b.x;
    c5 += w0 * r0b.y + w1 * r1b.y + w2v * r2b.y + w3 * r3b.y;
    c6 += w0 * r0b.z + w1 * r1b.z + w2v * r2b.z + w3 * r3b.z;
    c7 += w0 * r0b.w + w1 * r1b.w + w2v * r2b.w + w3 * r3b.w;
  }
  for (; e < deg; e += 2) {
    int ee = e + half;
    if (ee < deg) {
      int p = off + ee;
      int s = csr_src[p];
      float ww = ew[(size_t)p * 8 + h3];
      const float* rp = hb + (size_t)s * 256;
      float4 ra = *(const float4*)(rp), rb = *(const float4*)(rp + 4);
      sw += ww;
      c0 += ww * ra.x; c1 += ww * ra.y; c2 += ww * ra.z; c3 += ww * ra.w;
      c4 += ww * rb.x; c5 += ww * rb.y; c6 += ww * rb.z; c7 += ww * rb.w;
    }
  }
  // cross-half reduce: combine the two edge slots
  c0 += __shfl_xor(c0, 32); c1 += __shfl_xor(c1, 32);
  c2 += __shfl_xor(c2, 32); c3 += __shfl_xor(c3, 32);
  c4 += __shfl_xor(c4, 32); c5 += __shfl_xor(c5, 32);
  c6 += __shfl_xor(c6, 32); c7 += __shfl_xor(c7, 32);
  sw += __shfl_xor(sw, 32);
  const float inv = 1.f / (sw + 1e-16f);

  if (half == 0) {
    float4 ba = *(const float4*)(b1 + li * 8);
    float4 bbv = *(const float4*)(b1 + li * 8 + 4);
    rowbuf[w][RB(li * 8 + 0)] = fmaxf(c0 * inv + ba.x, 0.f);
    rowbuf[w][RB(li * 8 + 1)] = fmaxf(c1 * inv + ba.y, 0.f);
    rowbuf[w][RB(li * 8 + 2)] = fmaxf(c2 * inv + ba.z, 0.f);
    rowbuf[w][RB(li * 8 + 3)] = fmaxf(c3 * inv + ba.w, 0.f);
    rowbuf[w][RB(li * 8 + 4)] = fmaxf(c4 * inv + bbv.x, 0.f);
    rowbuf[w][RB(li * 8 + 5)] = fmaxf(c5 * inv + bbv.y, 0.f);
    rowbuf[w][RB(li * 8 + 6)] = fmaxf(c6 * inv + bbv.z, 0.f);
    rowbuf[w][RB(li * 8 + 7)] = fmaxf(c7 * inv + bbv.w, 0.f);
  }
  asm volatile("s_waitcnt lgkmcnt(0)" ::: "memory");

  // h2[n,o] = sum_cc relu_row[cc] * W2[cc,o]; grp-rotated walk; W2 from global (L1-hot)
  const int o = l & 15;
  const int grp = l >> 4;
  float a2 = 0.f;
#pragma unroll 8
  for (int t = 0; t < 64; ++t) {
    int cc = grp * 64 + ((t + grp * 8) & 63);
    a2 += rowbuf[w][RB(cc)] * W2[cc * 16 + o];
  }
  a2 += __shfl_xor(a2, 16);
  a2 += __shfl_xor(a2, 32);

  if (l < 16) {
    h2[(size_t)n * 16 + l] = a2;
    float ps = a2 * a_src2[l];
    float pd = a2 * a_dst2[l];
    ps += __shfl_xor(ps, 1); pd += __shfl_xor(pd, 1);
    ps += __shfl_xor(ps, 2); pd += __shfl_xor(pd, 2);
    ps += __shfl_xor(ps, 4); pd += __shfl_xor(pd, 4);
    ps += __shfl_xor(ps, 8); pd += __shfl_xor(pd, 8);
    if (l == 0) { als2[n] = ps; ald2[n] = pd; }
  }
}

// ============ GAT layer 2: single-pass aggregation (w computed inline, identical
// bits to old ew2 since csr_dst[p]==n) -> x1, g, keys + bucket hist ============
__global__ __launch_bounds__(256) void k_gat2(
    const float* __restrict__ h2, const float* __restrict__ als2,
    const float* __restrict__ ald2, const float* __restrict__ b2,
    const float* __restrict__ proj_w, const float* __restrict__ proj_b,
    const int* __restrict__ offsets, const int* __restrict__ csr_src,
    float* __restrict__ x1, float* __restrict__ g,
    unsigned long long* __restrict__ keys, int* __restrict__ bhist, int N) {
  const int w = threadIdx.x >> 6;
  const int l = threadIdx.x & 63;
  const int n = blockIdx.x * 4 + w;
  if (n >= N) return;
  const int off = offsets[n];
  const int deg = offsets[n + 1] - off;
  const float ad = ald2[n];
  const int slot = l >> 4;  // 4 parallel edge slots
  const int c = l & 15;

  float acc = 0.f, sw = 0.f;
  int e0 = 0;
  for (; e0 + 8 <= deg; e0 += 8) {
    int pA = off + e0 + slot;
    int pB = off + e0 + 4 + slot;
    int sA = csr_src[pA];
    int sB = csr_src[pB];
    float vA = als2[sA];
    float vB = als2[sB];
    float hA = h2[(size_t)sA * 16 + c];
    float hB = h2[(size_t)sB * 16 + c];
    float wA = expf(leakyrelu02(vA + ad));
    float wB = expf(leakyrelu02(vB + ad));
    sw += wA + wB;
    acc += wA * hA + wB * hB;
  }
  for (; e0 < deg; e0 += 4) {
    int e = e0 + slot;
    if (e < deg) {
      int p = off + e;
      int s = csr_src[p];
      float v = expf(leakyrelu02(als2[s] + ad));
      sw += v;
      acc += v * h2[(size_t)s * 16 + c];
    }
  }
  acc += __shfl_xor(acc, 16); sw += __shfl_xor(sw, 16);
  acc += __shfl_xor(acc, 32); sw += __shfl_xor(sw, 32);
  float x1v = acc / (sw + 1e-16f) + b2[c];

  float pg = x1v * proj_w[c];
  pg += __shfl_xor(pg, 1);
  pg += __shfl_xor(pg, 2);
  pg += __shfl_xor(pg, 4);
  pg += __shfl_xor(pg, 8);
  if (l < 16) x1[(size_t)n * 16 + l] = x1v;
  if (l == 0) {
    float gv = pg + proj_b[0];
    g[n] = gv;
    unsigned u = __float_as_uint(gv);
    u = (u & 0x80000000u) ? ~u : (u | 0x80000000u);
    keys[n] = (((unsigned long long)u) << 32) | (unsigned)n;
    atomicAdd(&bhist[u >> 16], 1);
  }
}

// ============ bucket scatter ============
__global__ __launch_bounds__(256) void k_bscatter(const unsigned long long* __restrict__ keys,
                                                  int* __restrict__ cursor,
                                                  unsigned long long* __restrict__ bkeys, int N) {
  int n = blockIdx.x * 256 + threadIdx.x;
  if (n >= N) return;
  unsigned long long k = keys[n];
  int b = (int)(k >> 48);
  int pos = atomicAdd(&cursor[b], 1);
  bkeys[pos] = k;
}

// ============ exact stable rank within bucket + scatter g*x1 to sorted order ============
__global__ __launch_bounds__(256) void k_brank(const unsigned long long* __restrict__ bkeys,
                                               const int* __restrict__ boffs,
                                               const float* __restrict__ g,
                                               const float* __restrict__ x1,
                                               int* __restrict__ rank,
                                               float* __restrict__ sortedv, int N) {
  int pos = blockIdx.x * 256 + threadIdx.x;
  if (pos >= N) return;
  unsigned long long k = bkeys[pos];
  int b = (int)(k >> 48);
  int lo = boffs[b], hi = boffs[b + 1];
  int r = lo;
  for (int j = lo; j < hi; ++j) r += (bkeys[j] < k) ? 1 : 0;
  int idx = (int)(unsigned)(k & 0xffffffffull);
  rank[idx] = r;
  float gv = g[idx];
#pragma unroll
  for (int c = 0; c < 16; c += 4) {
    float4 v = *(const float4*)(x1 + (size_t)idx * 16 + c);
    float4 o = make_float4(gv * v.x, gv * v.y, gv * v.z, gv * v.w);
    *(float4*)(sortedv + (size_t)r * 16 + c) = o;
  }
}

// ============ conv1d 'same', K=5, 16->16 channels ============
__global__ __launch_bounds__(256) void k_conv(const float* __restrict__ in,
                                              const float* __restrict__ wgt,
                                              const float* __restrict__ bias,
                                              float* __restrict__ out, int N, int relu) {
  __shared__ float s[260][17];
  __shared__ float ws[1280];
  __shared__ float bs[16];
  const int p0 = blockIdx.x * 256;
  for (int i = threadIdx.x; i < 1280; i += 256) ws[i] = wgt[i];
  if (threadIdx.x < 16) bs[threadIdx.x] = bias[threadIdx.x];
  for (int idx = threadIdx.x; idx < 260 * 16; idx += 256) {
    int lp = idx >> 4, c = idx & 15;
    int gp = p0 - 2 + lp;
    s[lp][c] = (gp >= 0 && gp < N) ? in[(size_t)gp * 16 + c] : 0.f;
  }
  __syncthreads();
  const int p = p0 + threadIdx.x;
  if (p >= N) return;
  float acc[16];
#pragma unroll
  for (int o = 0; o < 16; ++o) acc[o] = bs[o];
  for (int k = 0; k < 5; ++k) {
    for (int c = 0; c < 16; ++c) {
      float xv = s[threadIdx.x + k][c];
#pragma unroll
      for (int o = 0; o < 16; ++o) acc[o] += ws[(o * 16 + c) * 5 + k] * xv;
    }
  }
#pragma unroll
  for (int o = 0; o < 16; ++o) {
    float v = acc[o];
    if (relu) v = fmaxf(v, 0.f);
    out[(size_t)p * 16 + o] = v;
  }
}

// ============ final: concat(x1, x2=conv2[rank]) @ lin_w + lin_b -> log_softmax ============
__global__ __launch_bounds__(256) void k_final(
    const float* __restrict__ x1, const float* __restrict__ c2out,
    const int* __restrict__ rank, const float* __restrict__ lin_w,
    const float* __restrict__ lin_b, float* __restrict__ out, int N) {
  __shared__ float lw[512];
  __shared__ float lb[16];
  for (int i = threadIdx.x; i < 512; i += 256) lw[i] = lin_w[i];
  if (threadIdx.x < 16) lb[threadIdx.x] = lin_b[threadIdx.x];
  __syncthreads();
  const int n = blockIdx.x * 256 + threadIdx.x;
  if (n >= N) return;
  float xa[16], xb[16];
  const int r = rank[n];
#pragma unroll
  for (int c = 0; c < 16; c += 4) {
    float4 va = *(const float4*)(x1 + (size_t)n * 16 + c);
    float4 vb = *(const float4*)(c2out + (size_t)r * 16 + c);
    xa[c] = va.x; xa[c + 1] = va.y; xa[c + 2] = va.z; xa[c + 3] = va.w;
    xb[c] = vb.x; xb[c + 1] = vb.y; xb[c + 2] = vb.z; xb[c + 3] = vb.w;
  }
  float z[16];
#pragma unroll
  for (int o = 0; o < 16; ++o) z[o] = lb[o];
#pragma unroll
  for (int c = 0; c < 16; ++c) {
    float va = xa[c], vb = xb[c];
#pragma unroll
    for (int o = 0; o < 16; ++o) z[o] += va * lw[c * 16 + o] + vb * lw[(16 + c) * 16 + o];
  }
  float m = z[0];
#pragma unroll
  for (int o = 1; o < 16; ++o) m = fmaxf(m, z[o]);
  float ssum = 0.f;
#pragma unroll
  for (int o = 0; o < 16; ++o) ssum += expf(z[o] - m);
  float lse = m + logf(ssum);
#pragma unroll
  for (int o = 0; o < 16; ++o) out[(size_t)n * 16 + o] = z[o] - lse;
}

extern "C" void kernel_launch(void* const* d_in, const int* in_sizes, int n_in,
                              void* d_out, int out_size, void* d_ws, size_t ws_size,
                              hipStream_t stream) {
  const float* x = (const float*)d_in[0];
  const int* ei = (const int*)d_in[1];
  const float* W1 = (const float*)d_in[2];
  const float* a_src1 = (const float*)d_in[3];
  const float* a_dst1 = (const float*)d_in[4];
  const float* b1 = (const float*)d_in[5];
  const float* W2 = (const float*)d_in[6];
  const float* a_src2 = (const float*)d_in[7];
  const float* a_dst2 = (const float*)d_in[8];
  const float* b2 = (const float*)d_in[9];
  const float* proj_w = (const float*)d_in[10];
  const float* proj_b = (const float*)d_in[11];
  const float* c1_w = (const float*)d_in[12];
  const float* c1_b = (const float*)d_in[13];
  const float* c2_w = (const float*)d_in[14];
  const float* c2_b = (const float*)d_in[15];
  const float* lin_w = (const float*)d_in[16];
  const float* lin_b = (const float*)d_in[17];
  float* out = (float*)d_out;

  const int N = in_sizes[0] / 256;
  const int E = in_sizes[1] / 2;
  const int Etot = E + N;

  // CSR scan padding: 1024 threads x chunk, chunk multiple of 4
  int chunk = (N + 1023) / 1024;
  chunk = (chunk + 3) & ~3;
  const int Npad = 1024 * chunk;

  char* ws = (char*)d_ws;
  size_t off = 0;
  auto alloc = [&](size_t bytes) -> void* {
    void* p = ws + off;
    off = (off + bytes + 255) & ~(size_t)255;
    return p;
  };
  float* h_lin = (float*)alloc((size_t)N * 256 * 4);
  float* als1 = (float*)alloc((size_t)N * 8 * 4);
  float* ald1 = (float*)alloc((size_t)N * 8 * 4);
  int* counts = (int*)alloc((size_t)Npad * 4);
  int* offsets = (int*)alloc((size_t)(Npad + 1) * 4);
  int* cursor = (int*)alloc((size_t)Npad * 4);
  int* csr_src = (int*)alloc((size_t)Etot * 4);
  float* ew = (float*)alloc((size_t)Etot * 8 * 4);
  float* h2 = (float*)alloc((size_t)N * 16 * 4);
  float* als2 = (float*)alloc((size_t)N * 4);
  float* ald2 = (float*)alloc((size_t)N * 4);
  float* x1 = (float*)alloc((size_t)N * 16 * 4);
  float* gbuf = (float*)alloc((size_t)N * 4);
  unsigned long long* keys = (unsigned long long*)alloc((size_t)N * 8);
  int* bhist = (int*)alloc((size_t)NBUCKET * 4);
  int* boffs = (int*)alloc((size_t)(NBUCKET + 1) * 4);
  int* bcursor = (int*)alloc((size_t)NBUCKET * 4);
  unsigned long long* bkeys = (unsigned long long*)alloc((size_t)N * 8);
  int* rank = (int*)alloc((size_t)N * 4);
  float* sortedv = (float*)alloc((size_t)N * 16 * 4);
  float* c1out = (float*)alloc((size_t)N * 16 * 4);
  float* c2out = (float*)alloc((size_t)N * 16 * 4);
  if (off > ws_size) return;  // fail loudly rather than corrupt memory

  hipMemsetAsync(counts, 0, (size_t)Npad * 4, stream);
  hipMemsetAsync(bhist, 0, (size_t)NBUCKET * 4, stream);

  dim3 gg((N + 63) / 64, 4);
  k_gemm1<<<gg, 256, 0, stream>>>(x, W1, h_lin, a_src1, a_dst1, als1, ald1, N);
  k_hist<<<(Etot + 255) / 256, 256, 0, stream>>>(ei, counts, E, N);
  k_scan<<<1, 1024, 0, stream>>>(counts, offsets, cursor, chunk);
  k_scatter_ew<<<(Etot + 255) / 256, 256, 0, stream>>>(ei, als1, ald1, cursor,
                                                       csr_src, ew, E, N);
  k_gat1<<<(N + 3) / 4, 256, 0, stream>>>(h_lin, ew, b1, offsets, csr_src,
                                          W2, a_src2, a_dst2, h2, als2, ald2, N);
  k_gat2<<<(N + 3) / 4, 256, 0, stream>>>(h2, als2, ald2, b2, proj_w, proj_b,
                                          offsets, csr_src, x1, gbuf, keys, bhist, N);
  k_scan<<<1, 1024, 0, stream>>>(bhist, boffs, bcursor, NBUCKET / 1024);
  k_bscatter<<<(N + 255) / 256, 256, 0, stream>>>(keys, bcursor, bkeys, N);
  k_brank<<<(N + 255) / 256, 256, 0, stream>>>(bkeys, boffs, gbuf, x1, rank, sortedv, N);
  k_conv<<<(N + 255) / 256, 256, 0, stream>>>(sortedv, c1_w, c1_b, c1out, N, 1);
  k_conv<<<(N + 255) / 256, 256, 0, stream>>>(c1out, c2_w, c2_b, c2out, N, 0);
  k_final<<<(N + 255) / 256, 256, 0, stream>>>(x1, c2out, rank, lin_w, lin_b, out, N);
}